// Round 1
// baseline (4319.345 us; speedup 1.0000x reference)
//
#include <hip/hip_runtime.h>

#define NNODES 200000
#define NEDGES 6400000
#define INDIM  1433
#define NHID   16
#define OUTDIM 7

// ---------------------------------------------------------------------------
// K1: XW1 = feature @ W1   (tall-skinny GEMM, fp32, memory-bound)
// block = 512 threads (8 waves); each wave computes 8 node-rows.
// Lane l handles k-indices {base + l}: feature loads are coalesced (stride-1
// across lanes), W1 is staged transposed in LDS so w1t[j][k] reads are
// stride-1 across lanes -> conflict-free b32 reads.
// K staged in 2 chunks (704 + 729) so LDS = 16*769*4 = 48.1 KB -> 3 blocks/CU
// by LDS; VGPR (~190 incl. 128 accumulators) caps at 2 waves/SIMD.
// ---------------------------------------------------------------------------
constexpr int KC   = 769;          // padded LDS row stride (odd -> staggered banks)
constexpr int LEN0 = 704;          // 11 * 64, exact steps
constexpr int LEN1 = INDIM - LEN0; // 729 -> 12 steps, last step masked

__global__ __launch_bounds__(512, 2)
void gemm1(const float* __restrict__ feat, const float* __restrict__ W1,
           float* __restrict__ XW1) {
    __shared__ float w1t[NHID][KC];
    const int tid  = threadIdx.x;
    const int lane = tid & 63;
    const int wave = tid >> 6;
    const int nodeBase = blockIdx.x * 64 + wave * 8;

    float acc[8][NHID];
#pragma unroll
    for (int n = 0; n < 8; ++n)
#pragma unroll
        for (int j = 0; j < NHID; ++j) acc[n][j] = 0.f;

    int c0 = 0;
#pragma unroll
    for (int chunk = 0; chunk < 2; ++chunk) {
        const int len = (chunk == 0) ? LEN0 : LEN1;
        __syncthreads();   // protect previous chunk's readers
        // stage W1[c0 .. c0+len) transposed into LDS; zero the pad
        for (int idx = tid; idx < NHID * KC; idx += 512) {
            int kk = idx >> 4;   // 0..768
            int j  = idx & 15;
            float v = (kk < len) ? W1[(c0 + kk) * NHID + j] : 0.f;
            w1t[j][kk] = v;
        }
        __syncthreads();

        const int steps = (len + 63) >> 6;
        for (int s = 0; s < steps; ++s) {
            const int klocal = s * 64 + lane;
            const bool ok = (klocal < len);
            const int kg = c0 + klocal;
            float f[8];
#pragma unroll
            for (int n = 0; n < 8; ++n)
                f[n] = ok ? feat[(nodeBase + n) * INDIM + kg] : 0.f;
            float w[NHID];
#pragma unroll
            for (int j = 0; j < NHID; ++j) w[j] = w1t[j][klocal];
#pragma unroll
            for (int n = 0; n < 8; ++n)
#pragma unroll
                for (int j = 0; j < NHID; ++j)
                    acc[n][j] = fmaf(f[n], w[j], acc[n][j]);
        }
        c0 += len;
    }

    // cross-lane reduction: butterfly each (n,j), collect j into lane j
#pragma unroll
    for (int n = 0; n < 8; ++n) {
        float r = 0.f;
#pragma unroll
        for (int j = 0; j < NHID; ++j) {
            float v = acc[n][j];
#pragma unroll
            for (int off = 32; off > 0; off >>= 1) v += __shfl_xor(v, off, 64);
            if (lane == j) r = v;
        }
        if (lane < NHID) XW1[(nodeBase + n) * NHID + lane] = r;
    }
}

// ---------------------------------------------------------------------------
// init: H = 0, out = broadcast(b2)   (ws/out are poisoned 0xAA by harness)
// ---------------------------------------------------------------------------
__global__ void initbufs(float* __restrict__ H, float* __restrict__ out,
                         const float* __restrict__ b2) {
    int i = blockIdx.x * 256 + threadIdx.x;
    if (i < NNODES * NHID) H[i] = 0.f;
    if (i < NNODES * OUTDIM) out[i] = b2[i % OUTDIM];
}

// ---------------------------------------------------------------------------
// K2: H[row] += val * XW1[col]   (thread per (edge, j); 102.4M fp32 atomics)
// ---------------------------------------------------------------------------
__global__ void spmm1(const int* __restrict__ row, const int* __restrict__ col,
                      const float* __restrict__ vals,
                      const float* __restrict__ XW1, float* __restrict__ H) {
    int idx = blockIdx.x * 256 + threadIdx.x;   // < 102,400,000
    int e = idx >> 4, j = idx & 15;
    if (e >= NEDGES) return;
    int r = row[e], c = col[e];
    float v = vals[e];
    float x = XW1[c * NHID + j];
    __hip_atomic_fetch_add(&H[r * NHID + j], v * x,
                           __ATOMIC_RELAXED, __HIP_MEMORY_SCOPE_AGENT);
}

// ---------------------------------------------------------------------------
// K3: G = relu(H + b1) @ W2   (thread per node; W2/b1 are wave-uniform)
// ---------------------------------------------------------------------------
__global__ void layer2(const float* __restrict__ H, const float* __restrict__ b1,
                       const float* __restrict__ W2, float* __restrict__ G) {
    int n = blockIdx.x * 256 + threadIdx.x;
    if (n >= NNODES) return;
    float t[NHID];
#pragma unroll
    for (int k = 0; k < NHID; ++k)
        t[k] = fmaxf(H[n * NHID + k] + b1[k], 0.f);
#pragma unroll
    for (int j = 0; j < OUTDIM; ++j) {
        float s = 0.f;
#pragma unroll
        for (int k = 0; k < NHID; ++k)
            s = fmaf(t[k], W2[k * OUTDIM + j], s);
        G[n * OUTDIM + j] = s;
    }
}

// ---------------------------------------------------------------------------
// K4: out[row] += val * G[col]   (8 threads/edge, j<7 active; 44.8M atomics)
// ---------------------------------------------------------------------------
__global__ void spmm2(const int* __restrict__ row, const int* __restrict__ col,
                      const float* __restrict__ vals,
                      const float* __restrict__ G, float* __restrict__ out) {
    int idx = blockIdx.x * 256 + threadIdx.x;   // < 51,200,000
    int e = idx >> 3, j = idx & 7;
    if (e >= NEDGES || j >= OUTDIM) return;
    int r = row[e], c = col[e];
    float v = vals[e];
    float g = G[c * OUTDIM + j];
    __hip_atomic_fetch_add(&out[r * OUTDIM + j], v * g,
                           __ATOMIC_RELAXED, __HIP_MEMORY_SCOPE_AGENT);
}

extern "C" void kernel_launch(void* const* d_in, const int* in_sizes, int n_in,
                              void* d_out, int out_size, void* d_ws, size_t ws_size,
                              hipStream_t stream) {
    const float* feat  = (const float*)d_in[0];
    const int*   erow  = (const int*)  d_in[1];
    const int*   ecol  = (const int*)  d_in[2];
    const float* evals = (const float*)d_in[3];
    const float* W1    = (const float*)d_in[4];
    const float* b1    = (const float*)d_in[5];
    const float* W2    = (const float*)d_in[6];
    const float* b2    = (const float*)d_in[7];
    float* out = (float*)d_out;

    float* ws  = (float*)d_ws;
    float* XW1 = ws;                          // 3.2M floats
    float* H   = ws + (size_t)NNODES * NHID;  // 3.2M floats
    float* G   = ws;                          // reuse XW1 region (1.4M floats)

    initbufs<<<(NNODES * NHID + 255) / 256, 256, 0, stream>>>(H, out, b2);
    gemm1<<<NNODES / 64, 512, 0, stream>>>(feat, W1, XW1);
    spmm1<<<(NEDGES * NHID) / 256, 256, 0, stream>>>(erow, ecol, evals, XW1, H);
    layer2<<<(NNODES + 255) / 256, 256, 0, stream>>>(H, b1, W2, G);
    spmm2<<<(NEDGES * 8) / 256, 256, 0, stream>>>(erow, ecol, evals, G, out);
}